// Round 11
// baseline (1430.681 us; speedup 1.0000x reference)
//
#include <hip/hip_runtime.h>
#include <math.h>

// Sinkhorn regularized transport, B=8, m=n=1024, fp32, 100 iterations.
//
// R15: LL64 tagged packets built from R4's OWN 8B agent-scope atomics.
// R14 post-mortem: per-wave stamps/polls made it 2.1x SLOWER (532->1133us,
// same traffic, pure stall) -- R4's block barrier + all-32 polls were not a
// straggler tax, they ENFORCED grid lockstep that kept polls nearly free.
// Aggregation is cheap; desynchronization is expensive. Reverted.
// This round removes serialized L3 transactions instead, keeping lockstep:
//  - R4 critical path per hop-pair: data st8 -> drain -> stamp publish ->
//    poll detect -> data ld8 (4+ serialized L3 RTTs, twice per iter).
//  - LL64: pack (f32 payload, i32 tag) in ONE u64 __hip_atomic_store (the
//    exact st8/ld8 primitive family R4 proved; 8B atomicity is language-
//    guaranteed -- unlike R8-R11's asm dwordx4, whose dword-granular commit
//    reorder is the best explanation of those failures). Consumers spin
//    directly on the data packets: stamps, publish drains, and one barrier
//    per iteration disappear; hop-pair = store -> tagged-read.
//  - Lockstep overwrite-safety (R4's argument, unchanged): all consumers of
//    iter k's v finish before any owner stores v[k+1]; owner reads of
//    partials[k] complete before any producer stores partials[k+1]. Tags
//    additionally reject any stale iteration. Single-copy buffers.
//  - Cross-replay tag aliasing killed by memsetting the packet region each
//    launch (graph-ordered; memset->atomic-load visibility is R4-proven).
//  - Bounded spins (2^18) + workgroup-atomic dead-latch: a real stall fails
//    visibly in <100ms, never hangs.
// Reduce order is bit-identical to R4 -> absmax 5.96e-8 expected.
// Prediction: dur 532 -> ~400-460us; WRITE 248->~350MB (tag bytes),
// FETCH 70->~90MB (spin re-reads); VALUBusy ~14%.

#define B_    8
#define N_    1024
#define G_    32          // blocks per batch
#define RPB   32          // rows per block
#define KSTR  1028        // LDS row stride (floats): 16B aligned, bank skew
#define NITER 100
#define TPB   256
#define LMB   10.0f
#define MAXD  5.0f

// LDS: Kl (RPB*KSTR) + vl (N_) + ul (RPB) + red (G_ float4) + ctl (4 ints)
#define LDS_FLOATS (RPB * KSTR + N_ + RPB + 4 * G_ + 4)

typedef unsigned long long u64;

// ---- LL64 packet: one 8B agent-scope atomic = payload (lo) + tag (hi) ----
__device__ __forceinline__ void stp(u64* p, float d, int tag) {
    u64 raw = ((u64)(unsigned)tag << 32) | (u64)__float_as_uint(d);
    __hip_atomic_store(p, raw, __ATOMIC_RELAXED, __HIP_MEMORY_SCOPE_AGENT);
}
__device__ __forceinline__ int dead_ld(int* dead) {
    return __hip_atomic_load(dead, __ATOMIC_RELAXED,
                             __HIP_MEMORY_SCOPE_WORKGROUP);
}
__device__ __forceinline__ void dead_st(int* dead) {
    __hip_atomic_store(dead, 1, __ATOMIC_RELAXED,
                       __HIP_MEMORY_SCOPE_WORKGROUP);
}
// Spin-read 4 consecutive packets until all carry tag (or dead-latch).
// 4 independent loads per probe -> one ~L3-RTT round; self-throttling.
__device__ __forceinline__ float4 ldp4(const u64* p, int tag, int* dead) {
    u64 r0, r1, r2, r3;
    int spin = 0;
    for (;;) {
        r0 = __hip_atomic_load(p + 0, __ATOMIC_RELAXED,
                               __HIP_MEMORY_SCOPE_AGENT);
        r1 = __hip_atomic_load(p + 1, __ATOMIC_RELAXED,
                               __HIP_MEMORY_SCOPE_AGENT);
        r2 = __hip_atomic_load(p + 2, __ATOMIC_RELAXED,
                               __HIP_MEMORY_SCOPE_AGENT);
        r3 = __hip_atomic_load(p + 3, __ATOMIC_RELAXED,
                               __HIP_MEMORY_SCOPE_AGENT);
        if (((int)(r0 >> 32) == tag) && ((int)(r1 >> 32) == tag) &&
            ((int)(r2 >> 32) == tag) && ((int)(r3 >> 32) == tag)) break;
        if (++spin > (1 << 18) || dead_ld(dead)) { dead_st(dead); break; }
    }
    return make_float4(__uint_as_float((unsigned)r0),
                       __uint_as_float((unsigned)r1),
                       __uint_as_float((unsigned)r2),
                       __uint_as_float((unsigned)r3));
}

__global__ void __launch_bounds__(TPB, 1)
sinkhorn_kernel(const float* __restrict__ Mg,
                float* __restrict__ Pg,
                u64* __restrict__ partT,     // [B_][G_][N_] tagged packets
                u64* __restrict__ vT)        // [B_][N_]     tagged packets
{
    extern __shared__ float lds[];
    float* Kl   = lds;                        // RPB x KSTR
    float* vl   = lds + RPB * KSTR;           // N_
    float* ul   = vl + N_;                    // RPB
    float4* red = (float4*)(ul + RPB);        // G_ float4 (16B-aligned)
    int*   ctl  = (int*)(red + G_);           // [0] = dead latch

    const int b    = blockIdx.x & (B_ - 1);
    const int g    = blockIdx.x >> 3;
    const int t    = threadIdx.x;
    const int row0 = g * RPB;
    const float r = 1.0f / (float)N_;
    const float c = 1.0f / (float)N_;
    int* dead = ctl;

    u64* partb = partT + ((size_t)b * G_ + g) * N_;   // own partial slot
    u64* vb    = vT + (size_t)b * N_;

    // ---- stage K rows into LDS ----
    const float* Mb = Mg + ((size_t)b * N_ + row0) * N_;
    for (int i = 0; i < RPB; ++i) {
        float4 m4 = ((const float4*)(Mb + (size_t)i * N_))[t];
        float4 k4;
        k4.x = expf(-LMB * fminf(m4.x, MAXD));
        k4.y = expf(-LMB * fminf(m4.y, MAXD));
        k4.z = expf(-LMB * fminf(m4.z, MAXD));
        k4.w = expf(-LMB * fminf(m4.w, MAXD));
        *(float4*)&Kl[i * KSTR + 4 * t] = k4;
    }
    if (t < RPB) ul[t] = r;             // u = r initially
    if (t == 0) ctl[0] = 0;
    __syncthreads();

    for (int it = 0; it <= NITER; ++it) {
        const int tgtA = it + 1;                 // partial tag
        const int tgtV = (1 << 30) + it + 1;     // v tag (distinct space)

        // ---- phase A: partial[j] = sum_{own rows i} K[i][j] * u_i ----
        float4 a = make_float4(0.f, 0.f, 0.f, 0.f);
#pragma unroll
        for (int i = 0; i < RPB; ++i) {
            const float u  = ul[i];
            const float4 k4 = *(const float4*)&Kl[i * KSTR + 4 * t];
            a.x = fmaf(k4.x, u, a.x);
            a.y = fmaf(k4.y, u, a.y);
            a.z = fmaf(k4.z, u, a.z);
            a.w = fmaf(k4.w, u, a.w);
        }
        // fire-and-forget tagged packets (no drain, no stamp, no barrier)
        stp(&partb[4 * t + 0], a.x, tgtA);
        stp(&partb[4 * t + 1], a.y, tgtA);
        stp(&partb[4 * t + 2], a.z, tgtA);
        stp(&partb[4 * t + 3], a.w, tgtA);

        // ---- owner-reduce: block g owns cols [32g, 32g+32) ----
        {
            const int gp = t >> 3;           // producer 0..31
            const int q  = t & 7;            // col quad within our slice
            const u64* pb = partT + ((size_t)b * G_ + gp) * N_
                          + 32 * g + 4 * q;
            float4 acc = ldp4(pb, tgtA, dead);
            // reduce across the wave's 8 producers (lane bits 3..5)
#pragma unroll
            for (int d = 8; d <= 32; d <<= 1) {
                acc.x += __shfl_xor(acc.x, d);
                acc.y += __shfl_xor(acc.y, d);
                acc.z += __shfl_xor(acc.z, d);
                acc.w += __shfl_xor(acc.w, d);
            }
            const int wv = t >> 6;
            if ((t & 63) < 8) red[wv * 8 + (t & 63)] = acc;
        }
        __syncthreads();
        if (t < 8) {
            float4 y4;
            y4.x = red[t].x + red[8 + t].x + red[16 + t].x + red[24 + t].x;
            y4.y = red[t].y + red[8 + t].y + red[16 + t].y + red[24 + t].y;
            y4.z = red[t].z + red[8 + t].z + red[16 + t].z + red[24 + t].z;
            y4.w = red[t].w + red[8 + t].w + red[16 + t].w + red[24 + t].w;
            stp(&vb[32 * g + 4 * t + 0], c / y4.x, tgtV);
            stp(&vb[32 * g + 4 * t + 1], c / y4.y, tgtV);
            stp(&vb[32 * g + 4 * t + 2], c / y4.z, tgtV);
            stp(&vb[32 * g + 4 * t + 3], c / y4.w, tgtV);
        }

        // ---- broadcast: each thread spin-reads its v packets into LDS ----
        {
            float4 w = ldp4(&vb[4 * t], tgtV, dead);
            *(float4*)&vl[4 * t] = w;
        }
        __syncthreads();

        if (it == NITER) break;              // vl holds final v

        // ---- phase B: z_i = sum_j K[i][j] v_j ; u_i = r / z_i ----
        const int rI = t >> 3;               // 0..31 (row within block)
        const int l  = t & 7;                // 0..7  (8 lanes per row)
        float4 za = make_float4(0.f, 0.f, 0.f, 0.f);
#pragma unroll
        for (int k2 = 0; k2 < 32; ++k2) {
            const int j0 = 4 * l + 32 * k2;
            const float4 k4 = *(const float4*)&Kl[rI * KSTR + j0];
            const float4 vv = *(const float4*)&vl[j0];
            za.x = fmaf(k4.x, vv.x, za.x);
            za.y = fmaf(k4.y, vv.y, za.y);
            za.z = fmaf(k4.z, vv.z, za.z);
            za.w = fmaf(k4.w, vv.w, za.w);
        }
        float z = za.x + za.y + za.z + za.w;
        z += __shfl_xor(z, 1);
        z += __shfl_xor(z, 2);
        z += __shfl_xor(z, 4);
        if (l == 0) ul[rI] = r / z;
        __syncthreads();
    }

    // ---- epilogue: P[i][j] = u_i * K[i][j] * v_j ----
    float* Pb = Pg + ((size_t)b * N_ + row0) * N_;
    const float4 v4 = *(const float4*)&vl[4 * t];
    for (int i = 0; i < RPB; ++i) {
        const float u  = ul[i];
        const float4 k4 = *(const float4*)&Kl[i * KSTR + 4 * t];
        float4 p4;
        p4.x = u * k4.x * v4.x;
        p4.y = u * k4.y * v4.y;
        p4.z = u * k4.z * v4.z;
        p4.w = u * k4.w * v4.w;
        ((float4*)(Pb + (size_t)i * N_))[t] = p4;
    }
}

extern "C" void kernel_launch(void* const* d_in, const int* in_sizes, int n_in,
                              void* d_out, int out_size, void* d_ws, size_t ws_size,
                              hipStream_t stream) {
    const float* M = (const float*)d_in[0];
    float* P = (float*)d_out;

    const size_t part_pkts = (size_t)B_ * G_ * N_;   // 2 MB of u64
    const size_t v_pkts    = (size_t)B_ * N_;        // 64 KB of u64
    u64* partT = (u64*)d_ws;
    u64* vT    = partT + part_pkts;
    // Zero ALL packet tags each launch (graph-ordered, ~2.1MB): prevents a
    // prior replay's tags (which repeat the same 1..101 sequence) from
    // validating stale data. Memset->atomic-load visibility is R4-proven.
    (void)hipMemsetAsync(partT, 0, (part_pkts + v_pkts) * sizeof(u64),
                         stream);

    const size_t lds_bytes = (size_t)LDS_FLOATS * sizeof(float);
    (void)hipFuncSetAttribute((const void*)sinkhorn_kernel,
                              hipFuncAttributeMaxDynamicSharedMemorySize,
                              (int)lds_bytes);

    void* args[] = { (void*)&M, (void*)&P, (void*)&partT, (void*)&vT };
    hipError_t e = hipLaunchCooperativeKernel((void*)sinkhorn_kernel,
                                              dim3(B_ * G_), dim3(TPB),
                                              args, (unsigned)lds_bytes, stream);
    if (e != hipSuccess) {
        // fallback: 256 blocks at 1 block/CU on 256 CUs is co-resident,
        // which the packet dataflow requires
        sinkhorn_kernel<<<dim3(B_ * G_), dim3(TPB), lds_bytes, stream>>>(
            M, P, partT, vT);
    }
}

// Round 12
// 734.441 us; speedup vs baseline: 1.9480x; 1.9480x over previous
//
#include <hip/hip_runtime.h>
#include <math.h>

// Sinkhorn regularized transport, B=8, m=n=1024, fp32, 100 iterations.
//
// R16: self-validating data packets -- "nonzero = valid" -- with slot
// rotation + reader-side re-zeroing. No stamps, no publishes, no polls.
//
// Arc evidence: R4 structure = 532us (banked). R14 (per-wave stamps): +113%
// -- desync is expensive. R15 (tag-per-float LL64): +150% -- 2x store
// transactions + tag bytes blew WRITE to 886MB. Lesson: R4's traffic shape
// is minimal; only the SERIALIZED TRANSACTION COUNT is attackable.
// R4's chain per hop: data-store -> barrier-drain -> stamp-publish(1 RTT)
// -> poll-detect(1 RTT) -> data-read. The publish+detect pair is deletable
// because the data validates itself: partials and v are STRICTLY POSITIVE
// (sums/ratios of exponentials), so a zeroed 8B slot reads 0 until the real
// packet lands. Rests ONLY on R4-proven facts: (a) 8B agent-scope
// __hip_atomic store/load never tears (R4's st8/ld8); (b) __syncthreads'
// vmcnt drain puts prior agent stores at the coherence point.
//  - part: 2-slot ring [2][B][G][512] u64. Producer writes slot it&1; the
//    UNIQUE reader (owner thread) zeroes each element right after reading.
//    Zero drains at that iter's barrier; rewrite comes at it+2, ordered
//    after via (zero-drain -> barrier -> owner v-write -> producer observes
//    v -> rewrite): coherence-point order guaranteed.
//  - v: 4-slot ring [4][B][512] u64. Owner writes slot it&3, then zeroes
//    its slice of slot (it+2)&3 (readers of that slot finished at it-2;
//    barrier-mediated ordering as above).
//  - Traffic: R4's data bytes + ~1MB/iter fire-and-forget zeroes. No tag
//    bytes, no stamp lines. Barriers 4/iter -> 3/iter.
//  - Memset (graph-ordered) zeroes rings at launch; replay-safe since every
//    slot is re-zeroed before reuse and memset re-arms each replay.
//  - Bounded spins (2^18) + LDS dead-latch: flaws fail visibly, never hang.
// Prediction: passes at 5.96e-8; dur 532 -> ~320-400us; WRITE ~330MB,
// FETCH ~90MB; VALUBusy ~15-18%. Regression => R4 is the structural floor.

#define B_    8
#define N_    1024
#define G_    32          // blocks per batch
#define RPB   32          // rows per block
#define KSTR  1028        // LDS row stride (floats): 16B aligned, bank skew
#define NITER 100
#define TPB   256
#define LMB   10.0f
#define MAXD  5.0f
#define NU    512         // u64 packets per 1024-float row

// LDS: Kl (RPB*KSTR) + vl (N_) + ul (RPB) + red (G_ float4) + ctl (4 ints)
#define LDS_FLOATS (RPB * KSTR + N_ + RPB + 4 * G_ + 4)

typedef unsigned long long u64;

// ---- 8B agent-scope packet ops (R4's proven st8/ld8 primitive family) ----
__device__ __forceinline__ void stp(u64* p, float a, float b) {
    float2 f2 = make_float2(a, b);
    __hip_atomic_store(p, __builtin_bit_cast(u64, f2),
                       __ATOMIC_RELAXED, __HIP_MEMORY_SCOPE_AGENT);
}
__device__ __forceinline__ void stz(u64* p) {
    __hip_atomic_store(p, 0ull, __ATOMIC_RELAXED, __HIP_MEMORY_SCOPE_AGENT);
}
__device__ __forceinline__ u64 ldp(const u64* p) {
    return __hip_atomic_load(p, __ATOMIC_RELAXED, __HIP_MEMORY_SCOPE_AGENT);
}
__device__ __forceinline__ int dead_ld(int* d) {
    return __hip_atomic_load(d, __ATOMIC_RELAXED,
                             __HIP_MEMORY_SCOPE_WORKGROUP);
}
__device__ __forceinline__ void dead_st(int* d) {
    __hip_atomic_store(d, 1, __ATOMIC_RELAXED, __HIP_MEMORY_SCOPE_WORKGROUP);
}
// Spin until both adjacent packets are nonzero (8B atomicity => a packet is
// all-zero or fully-new; payloads are strictly positive so nonzero = valid).
// Bounded + dead-latch: a real stall fails visibly, never hangs.
__device__ __forceinline__ float4 spin2(const u64* p, int* dead,
                                        u64& r0o, u64& r1o) {
    u64 r0, r1;
    int spin = 0;
    for (;;) {
        r0 = ldp(p);
        r1 = ldp(p + 1);
        if (r0 != 0ull && r1 != 0ull) break;
        if (dead_ld(dead) || ++spin > (1 << 18)) { dead_st(dead); break; }
        __builtin_amdgcn_s_sleep(1);
    }
    r0o = r0; r1o = r1;
    float2 f0 = __builtin_bit_cast(float2, r0);
    float2 f1 = __builtin_bit_cast(float2, r1);
    return make_float4(f0.x, f0.y, f1.x, f1.y);
}

__global__ void __launch_bounds__(TPB, 1)
sinkhorn_kernel(const float* __restrict__ Mg,
                float* __restrict__ Pg,
                u64* __restrict__ partR,     // [2][B_][G_][NU]
                u64* __restrict__ vR)        // [4][B_][NU]
{
    extern __shared__ float lds[];
    float* Kl   = lds;                        // RPB x KSTR
    float* vl   = lds + RPB * KSTR;           // N_
    float* ul   = vl + N_;                    // RPB
    float4* red = (float4*)(ul + RPB);        // G_ float4 (16B-aligned)
    int*   ctl  = (int*)(red + G_);           // [0] = dead latch

    const int b    = blockIdx.x & (B_ - 1);
    const int g    = blockIdx.x >> 3;
    const int t    = threadIdx.x;
    const int row0 = g * RPB;
    const float r = 1.0f / (float)N_;
    const float c = 1.0f / (float)N_;
    int* dead = ctl;

    // ---- stage K rows into LDS ----
    const float* Mb = Mg + ((size_t)b * N_ + row0) * N_;
    for (int i = 0; i < RPB; ++i) {
        float4 m4 = ((const float4*)(Mb + (size_t)i * N_))[t];
        float4 k4;
        k4.x = expf(-LMB * fminf(m4.x, MAXD));
        k4.y = expf(-LMB * fminf(m4.y, MAXD));
        k4.z = expf(-LMB * fminf(m4.z, MAXD));
        k4.w = expf(-LMB * fminf(m4.w, MAXD));
        *(float4*)&Kl[i * KSTR + 4 * t] = k4;
    }
    if (t < RPB) ul[t] = r;             // u = r initially
    if (t == 0) ctl[0] = 0;
    __syncthreads();

    for (int it = 0; it <= NITER; ++it) {
        u64* partS = partR + ((size_t)(it & 1) * B_ + b) * G_ * NU;
        u64* vS    = vR + ((size_t)(it & 3) * B_ + b) * NU;
        u64* vZ    = vR + ((size_t)((it + 2) & 3) * B_ + b) * NU;

        // ---- phase A: partial[j] = sum_{own rows i} K[i][j] * u_i ----
        float4 a = make_float4(0.f, 0.f, 0.f, 0.f);
#pragma unroll
        for (int i = 0; i < RPB; ++i) {
            const float u  = ul[i];
            const float4 k4 = *(const float4*)&Kl[i * KSTR + 4 * t];
            a.x = fmaf(k4.x, u, a.x);
            a.y = fmaf(k4.y, u, a.y);
            a.z = fmaf(k4.z, u, a.z);
            a.w = fmaf(k4.w, u, a.w);
        }
        // fire-and-forget: data IS the flag (strictly positive payload)
        stp(&partS[(size_t)g * NU + 2 * t],     a.x, a.y);
        stp(&partS[(size_t)g * NU + 2 * t + 1], a.z, a.w);

        // ---- owner-reduce: block g owns cols [32g, 32g+32) ----
        {
            const int gp = t >> 3;           // producer 0..31
            const int q  = t & 7;            // col quad within our slice
            u64* pb = partS + (size_t)gp * NU + 16 * g + 2 * q;
            u64 r0, r1;
            float4 acc = spin2(pb, dead, r0, r1);
            // unique reader: re-zero for the it+2 reuse of this slot
            stz(pb);
            stz(pb + 1);
            // reduce across the wave's 8 producers (lane bits 3..5)
#pragma unroll
            for (int d = 8; d <= 32; d <<= 1) {
                acc.x += __shfl_xor(acc.x, d);
                acc.y += __shfl_xor(acc.y, d);
                acc.z += __shfl_xor(acc.z, d);
                acc.w += __shfl_xor(acc.w, d);
            }
            const int wv = t >> 6;
            if ((t & 63) < 8) red[wv * 8 + (t & 63)] = acc;
        }
        __syncthreads();                     // also drains the zero-stores
        if (t < 8) {
            float4 y4;
            y4.x = red[t].x + red[8 + t].x + red[16 + t].x + red[24 + t].x;
            y4.y = red[t].y + red[8 + t].y + red[16 + t].y + red[24 + t].y;
            y4.z = red[t].z + red[8 + t].z + red[16 + t].z + red[24 + t].z;
            y4.w = red[t].w + red[8 + t].w + red[16 + t].w + red[24 + t].w;
            stp(&vS[16 * g + 2 * t],     c / y4.x, c / y4.y);
            stp(&vS[16 * g + 2 * t + 1], c / y4.z, c / y4.w);
            // pre-zero our slice of the slot that iter it+2 will use
            // (its readers finished at it-2; ordering via barrier drains)
            stz(&vZ[16 * g + 2 * t]);
            stz(&vZ[16 * g + 2 * t + 1]);
        }

        // ---- broadcast: each thread spin-reads its v packets into LDS ----
        {
            u64 r0, r1;
            float4 w = spin2(&vS[2 * t], dead, r0, r1);
            *(float4*)&vl[4 * t] = w;
        }
        __syncthreads();

        if (it == NITER) break;              // vl holds final v

        // ---- phase B: z_i = sum_j K[i][j] v_j ; u_i = r / z_i ----
        const int rI = t >> 3;               // 0..31 (row within block)
        const int l  = t & 7;                // 0..7  (8 lanes per row)
        float4 za = make_float4(0.f, 0.f, 0.f, 0.f);
#pragma unroll
        for (int k2 = 0; k2 < 32; ++k2) {
            const int j0 = 4 * l + 32 * k2;
            const float4 k4 = *(const float4*)&Kl[rI * KSTR + j0];
            const float4 vv = *(const float4*)&vl[j0];
            za.x = fmaf(k4.x, vv.x, za.x);
            za.y = fmaf(k4.y, vv.y, za.y);
            za.z = fmaf(k4.z, vv.z, za.z);
            za.w = fmaf(k4.w, vv.w, za.w);
        }
        float z = za.x + za.y + za.z + za.w;
        z += __shfl_xor(z, 1);
        z += __shfl_xor(z, 2);
        z += __shfl_xor(z, 4);
        if (l == 0) ul[rI] = r / z;
        __syncthreads();
    }

    // ---- epilogue: P[i][j] = u_i * K[i][j] * v_j ----
    float* Pb = Pg + ((size_t)b * N_ + row0) * N_;
    const float4 v4 = *(const float4*)&vl[4 * t];
    for (int i = 0; i < RPB; ++i) {
        const float u  = ul[i];
        const float4 k4 = *(const float4*)&Kl[i * KSTR + 4 * t];
        float4 p4;
        p4.x = u * k4.x * v4.x;
        p4.y = u * k4.y * v4.y;
        p4.z = u * k4.z * v4.z;
        p4.w = u * k4.w * v4.w;
        ((float4*)(Pb + (size_t)i * N_))[t] = p4;
    }
}

extern "C" void kernel_launch(void* const* d_in, const int* in_sizes, int n_in,
                              void* d_out, int out_size, void* d_ws, size_t ws_size,
                              hipStream_t stream) {
    const float* M = (const float*)d_in[0];
    float* P = (float*)d_out;

    const size_t part_pkts = (size_t)2 * B_ * G_ * NU;   // 2 MB
    const size_t v_pkts    = (size_t)4 * B_ * NU;        // 128 KB
    u64* partR = (u64*)d_ws;
    u64* vR    = partR + part_pkts;
    // Zero both rings each launch (graph-ordered). Within a launch every
    // slot is re-zeroed by its unique reader / owner before reuse, so no
    // in-kernel reset is ever needed; the memset re-arms each replay.
    (void)hipMemsetAsync(partR, 0, (part_pkts + v_pkts) * sizeof(u64),
                         stream);

    const size_t lds_bytes = (size_t)LDS_FLOATS * sizeof(float);
    (void)hipFuncSetAttribute((const void*)sinkhorn_kernel,
                              hipFuncAttributeMaxDynamicSharedMemorySize,
                              (int)lds_bytes);

    void* args[] = { (void*)&M, (void*)&P, (void*)&partR, (void*)&vR };
    hipError_t e = hipLaunchCooperativeKernel((void*)sinkhorn_kernel,
                                              dim3(B_ * G_), dim3(TPB),
                                              args, (unsigned)lds_bytes, stream);
    if (e != hipSuccess) {
        // fallback: 256 blocks at 1 block/CU on 256 CUs is co-resident,
        // which the packet dataflow requires
        sinkhorn_kernel<<<dim3(B_ * G_), dim3(TPB), lds_bytes, stream>>>(
            M, P, partR, vR);
    }
}

// Round 13
// 587.068 us; speedup vs baseline: 2.4370x; 1.2510x over previous
//
#include <hip/hip_runtime.h>
#include <math.h>

// Sinkhorn regularized transport, B=8, m=n=1024, fp32, 100 iterations.
//
// R17 = R12 (the 532us R4-protocol kernel, byte-identical sync) + ONE
// compute-side change: phase A reads K from per-thread REGISTERS.
// Arc evidence: R4=532us; every protocol restructure regressed (R13/14
// per-wave: 1133; R15 LL64 tags: 1345; R16 nonzero-valid: 660, +211MB
// zero-store traffic). Protocol is frozen forever. Remaining attackable
// cost per LDS accounting: ~262KB/CU/iter through the shared 128B/cy LDS
// pipe (~2048cy) + ~1044 conflict cy = ~1.3us of the 5.3us/iter, and LDS
// is serialized across the CU's 4 waves (VALU is parallel per-SIMD).
// Change: the K tile per thread is 32 rows x 4 cols = 32 float4 = 128
// VGPRs -> kreg[32] (fits: 44 -> ~170 VGPRs, 1 block/CU, 512/wave budget).
// K also stays in LDS for phase B (unchanged). Phase A: K from kreg, u
// read as 8 x b128 instead of 32 x b32. Epilogue uses kreg (one-time).
// Every FMA has identical operand values and order -> run is BIT-IDENTICAL
// to R4: absmax must be exactly 5.960464e-8.
// Prediction: dur 532 -> ~475-495us; VALUBusy ~12.5%; FETCH/WRITE
// unchanged (70/248MB); conflicts ~unchanged. No movement => re-bank R12
// as this dataflow's floor.

#define B_    8
#define N_    1024
#define G_    32          // blocks per batch
#define RPB   32          // rows per block
#define KSTR  1028        // LDS row stride (floats): 16B aligned, bank skew
#define NITER 100
#define TPB   256
#define LMB   10.0f
#define MAXD  5.0f

// LDS: Kl (RPB*KSTR) + vl (N_) + ul (RPB) + red (G_ float4)
#define LDS_FLOATS (RPB * KSTR + N_ + RPB + 4 * G_)

typedef unsigned long long u64;

__device__ __forceinline__ void st8(float* p, float a, float b) {
    float2 f2 = make_float2(a, b);
    __hip_atomic_store((u64*)p, __builtin_bit_cast(u64, f2),
                       __ATOMIC_RELAXED, __HIP_MEMORY_SCOPE_AGENT);
}
__device__ __forceinline__ float2 ld8(const float* p) {
    u64 raw = __hip_atomic_load((const u64*)p,
                                __ATOMIC_RELAXED, __HIP_MEMORY_SCOPE_AGENT);
    return __builtin_bit_cast(float2, raw);
}
__device__ __forceinline__ void publish(int* s, int v) {
    __atomic_signal_fence(__ATOMIC_SEQ_CST);
    __hip_atomic_store(s, v, __ATOMIC_RELAXED, __HIP_MEMORY_SCOPE_AGENT);
}
// Wait until all 32 stamps reach tgt. One coalesced 128B wave-load per poll
// (lanes duplicate the 32 stamps twice across the 64-lane vote).
__device__ __forceinline__ void poll32(const int* st, int tgt) {
    const int l = threadIdx.x & 31;
    for (;;) {
        int s = __hip_atomic_load(&st[l], __ATOMIC_RELAXED,
                                  __HIP_MEMORY_SCOPE_AGENT);
        if (__all(s >= tgt)) break;
        __builtin_amdgcn_s_sleep(2);
    }
    __atomic_signal_fence(__ATOMIC_SEQ_CST);
}

__global__ void __launch_bounds__(TPB, 1)
sinkhorn_kernel(const float* __restrict__ Mg,
                float* __restrict__ Pg,
                float* __restrict__ part,    // [2][B_][G_][N_]
                float* __restrict__ vbuf,    // [2][B_][N_]
                int* __restrict__ stA,       // [2][B_][G_]
                int* __restrict__ stV)       // [2][B_][G_]
{
    extern __shared__ float lds[];
    float* Kl   = lds;                        // RPB x KSTR
    float* vl   = lds + RPB * KSTR;           // N_
    float* ul   = vl + N_;                    // RPB
    float4* red = (float4*)(ul + RPB);        // G_ float4 (16B-aligned)

    const int b    = blockIdx.x & (B_ - 1);
    const int g    = blockIdx.x >> 3;
    const int t    = threadIdx.x;
    const int row0 = g * RPB;
    const float r = 1.0f / (float)N_;
    const float c = 1.0f / (float)N_;

    // ---- stage K rows into LDS AND per-thread registers ----
    // Thread t owns cols [4t,4t+4) of all 32 rows: 32 x float4 = 128 VGPRs.
    float4 kreg[RPB];
    const float* Mb = Mg + ((size_t)b * N_ + row0) * N_;
#pragma unroll
    for (int i = 0; i < RPB; ++i) {
        float4 m4 = ((const float4*)(Mb + (size_t)i * N_))[t];
        float4 k4;
        k4.x = expf(-LMB * fminf(m4.x, MAXD));
        k4.y = expf(-LMB * fminf(m4.y, MAXD));
        k4.z = expf(-LMB * fminf(m4.z, MAXD));
        k4.w = expf(-LMB * fminf(m4.w, MAXD));
        kreg[i] = k4;
        *(float4*)&Kl[i * KSTR + 4 * t] = k4;
    }
    if (t < RPB) ul[t] = r;             // u = r initially
    __syncthreads();

    for (int it = 0; it <= NITER; ++it) {
        const int p   = it & 1;
        const int tgt = it + 1;
        int* stA_pb = stA + ((size_t)p * B_ + b) * G_;
        int* stV_pb = stV + ((size_t)p * B_ + b) * G_;

        // ---- phase A: partial[j] = sum_{own rows i} K[i][j] * u_i ----
        // K from registers (zero LDS traffic); u as 8 x b128 broadcast
        // reads. FMA order identical to R4: i ascending, x,y,z,w.
        float4 a = make_float4(0.f, 0.f, 0.f, 0.f);
#pragma unroll
        for (int j = 0; j < RPB / 4; ++j) {
            const float4 u4 = *(const float4*)&ul[4 * j];
            a.x = fmaf(kreg[4*j+0].x, u4.x, a.x);
            a.y = fmaf(kreg[4*j+0].y, u4.x, a.y);
            a.z = fmaf(kreg[4*j+0].z, u4.x, a.z);
            a.w = fmaf(kreg[4*j+0].w, u4.x, a.w);
            a.x = fmaf(kreg[4*j+1].x, u4.y, a.x);
            a.y = fmaf(kreg[4*j+1].y, u4.y, a.y);
            a.z = fmaf(kreg[4*j+1].z, u4.y, a.z);
            a.w = fmaf(kreg[4*j+1].w, u4.y, a.w);
            a.x = fmaf(kreg[4*j+2].x, u4.z, a.x);
            a.y = fmaf(kreg[4*j+2].y, u4.z, a.y);
            a.z = fmaf(kreg[4*j+2].z, u4.z, a.z);
            a.w = fmaf(kreg[4*j+2].w, u4.z, a.w);
            a.x = fmaf(kreg[4*j+3].x, u4.w, a.x);
            a.y = fmaf(kreg[4*j+3].y, u4.w, a.y);
            a.z = fmaf(kreg[4*j+3].z, u4.w, a.z);
            a.w = fmaf(kreg[4*j+3].w, u4.w, a.w);
        }
        float* slot = part + (((size_t)p * B_ + b) * G_ + g) * N_;
        st8(&slot[4 * t],     a.x, a.y);
        st8(&slot[4 * t + 2], a.z, a.w);

        __syncthreads();                     // drain all waves' stores to L3
        if (t == 0) publish(&stA_pb[g], tgt);

        // ---- owner-reduce: block g owns cols [32g, 32g+32) ----
        poll32(stA_pb, tgt);
        {
            const int gp = t >> 3;           // producer 0..31
            const int q  = t & 7;            // col quad within our slice
            const float* pb = part + (((size_t)p * B_ + b) * G_ + gp) * N_
                            + 32 * g + 4 * q;
            float2 s0 = ld8(pb);
            float2 s1 = ld8(pb + 2);
            float4 acc = make_float4(s0.x, s0.y, s1.x, s1.y);
            // reduce across the wave's 8 producers (lane bits 3..5)
#pragma unroll
            for (int d = 8; d <= 32; d <<= 1) {
                acc.x += __shfl_xor(acc.x, d);
                acc.y += __shfl_xor(acc.y, d);
                acc.z += __shfl_xor(acc.z, d);
                acc.w += __shfl_xor(acc.w, d);
            }
            const int wv = t >> 6;
            if ((t & 63) < 8) red[wv * 8 + (t & 63)] = acc;
        }
        __syncthreads();
        float* vb = vbuf + ((size_t)p * B_ + b) * N_;
        if (t < 8) {
            float4 y4;
            y4.x = red[t].x + red[8 + t].x + red[16 + t].x + red[24 + t].x;
            y4.y = red[t].y + red[8 + t].y + red[16 + t].y + red[24 + t].y;
            y4.z = red[t].z + red[8 + t].z + red[16 + t].z + red[24 + t].z;
            y4.w = red[t].w + red[8 + t].w + red[16 + t].w + red[24 + t].w;
            st8(&vb[32 * g + 4 * t],     c / y4.x, c / y4.y);
            st8(&vb[32 * g + 4 * t + 2], c / y4.z, c / y4.w);
        }
        if (t == 0) {
            __atomic_signal_fence(__ATOMIC_SEQ_CST);
            __builtin_amdgcn_s_waitcnt(0);   // wave-0's v stores at L3
            publish(&stV_pb[g], tgt);
        }

        // ---- broadcast: everyone reads full v (4KB) into LDS ----
        poll32(stV_pb, tgt);
        {
            float2 w0 = ld8(&vb[4 * t]);
            float2 w1 = ld8(&vb[4 * t + 2]);
            *(float4*)&vl[4 * t] = make_float4(w0.x, w0.y, w1.x, w1.y);
        }
        __syncthreads();

        if (it == NITER) break;              // vl holds final v

        // ---- phase B: z_i = sum_j K[i][j] v_j ; u_i = r / z_i ----
        const int rI = t >> 3;               // 0..31 (row within block)
        const int l  = t & 7;                // 0..7  (8 lanes per row)
        float4 za = make_float4(0.f, 0.f, 0.f, 0.f);
#pragma unroll
        for (int k2 = 0; k2 < 32; ++k2) {
            const int j0 = 4 * l + 32 * k2;
            const float4 k4 = *(const float4*)&Kl[rI * KSTR + j0];
            const float4 vv = *(const float4*)&vl[j0];
            za.x = fmaf(k4.x, vv.x, za.x);
            za.y = fmaf(k4.y, vv.y, za.y);
            za.z = fmaf(k4.z, vv.z, za.z);
            za.w = fmaf(k4.w, vv.w, za.w);
        }
        float z = za.x + za.y + za.z + za.w;
        z += __shfl_xor(z, 1);
        z += __shfl_xor(z, 2);
        z += __shfl_xor(z, 4);
        if (l == 0) ul[rI] = r / z;
        __syncthreads();
    }

    // ---- epilogue: P[i][j] = u_i * K[i][j] * v_j (K from registers) ----
    float* Pb = Pg + ((size_t)b * N_ + row0) * N_;
    const float4 v4 = *(const float4*)&vl[4 * t];
#pragma unroll
    for (int i = 0; i < RPB; ++i) {
        const float u  = ul[i];
        const float4 k4 = kreg[i];
        float4 p4;
        p4.x = u * k4.x * v4.x;
        p4.y = u * k4.y * v4.y;
        p4.z = u * k4.z * v4.z;
        p4.w = u * k4.w * v4.w;
        ((float4*)(Pb + (size_t)i * N_))[t] = p4;
    }
}

extern "C" void kernel_launch(void* const* d_in, const int* in_sizes, int n_in,
                              void* d_out, int out_size, void* d_ws, size_t ws_size,
                              hipStream_t stream) {
    const float* M = (const float*)d_in[0];
    float* P = (float*)d_out;

    const size_t part_floats = (size_t)2 * B_ * G_ * N_;   // 2 MB
    const size_t v_floats    = (size_t)2 * B_ * N_;        // 64 KB
    float* part = (float*)d_ws;
    float* vbuf = part + part_floats;
    int*   stA  = (int*)(vbuf + v_floats);
    int*   stV  = stA + 2 * B_ * G_;
    (void)hipMemsetAsync(stA, 0, (size_t)4 * B_ * G_ * sizeof(int), stream);

    const size_t lds_bytes = (size_t)LDS_FLOATS * sizeof(float);
    (void)hipFuncSetAttribute((const void*)sinkhorn_kernel,
                              hipFuncAttributeMaxDynamicSharedMemorySize,
                              (int)lds_bytes);

    void* args[] = { (void*)&M, (void*)&P, (void*)&part, (void*)&vbuf,
                     (void*)&stA, (void*)&stV };
    hipError_t e = hipLaunchCooperativeKernel((void*)sinkhorn_kernel,
                                              dim3(B_ * G_), dim3(TPB),
                                              args, (unsigned)lds_bytes, stream);
    if (e != hipSuccess) {
        // fallback: 256 blocks at 1 block/CU on 256 CUs is co-resident,
        // which the stamp-flag dataflow requires
        sinkhorn_kernel<<<dim3(B_ * G_), dim3(TPB), lds_bytes, stream>>>(
            M, P, part, vbuf, stA, stV);
    }
}